// Round 19
// baseline (319.027 us; speedup 1.0000x reference)
//
#include <hip/hip_runtime.h>
#include <float.h>
#include <math.h>

// Problem constants (fixed by the reference)
constexpr int Cc = 19;    // classes
constexpr int Kk = 50;    // pca dim
constexpr int Dd = 256;   // feature dim

constexpr int NCOL = 64;          // padded cols per class (50 -> 64)
constexpr int CPAD = 20;          // classes incl 1 dummy pad class (Bs sizing)
constexpr int ROWS = CPAD * NCOL; // 1280 rows of the stacked B matrix
constexpr int MT   = 128;         // pixels per block
constexpr int THR  = 512;         // 8 waves

typedef float  f32x16 __attribute__((ext_vector_type(16)));
typedef short  bf16x8 __attribute__((ext_vector_type(8)));

__device__ __forceinline__ unsigned short f2bf(float x) {
  unsigned u = __float_as_uint(x);
  unsigned r = 0x7FFFu + ((u >> 16) & 1u);   // round-to-nearest-even
  return (unsigned short)((u + r) >> 16);
}
__device__ __forceinline__ float bf2f(unsigned short h) {
  return __uint_as_float(((unsigned)h) << 16);
}

// ---------------------------------------------------------------------------
// Prep 1+2 fused: rv = 1/sqrt(var); bc = mean_proj*rv + mu (LDS); Cholesky
// cov_inv = L L^T in LDS (element-parallel trailing update, R16); store
// Lmat and g = L^T bc (0-padded).
// ---------------------------------------------------------------------------
__global__ __launch_bounds__(256) void prepchol_kernel(
    const float* __restrict__ pca_mean,
    const float* __restrict__ comps,
    const float* __restrict__ var,
    const float* __restrict__ mu,
    const float* __restrict__ cov_inv,
    float* __restrict__ w_rv,
    float* __restrict__ Lmat,
    float* __restrict__ g) {
  __shared__ float M[Kk * Kk];
  __shared__ float bcs[Kk];
  const int c = blockIdx.x, t = threadIdx.x;

  if (t < Kk) {
    const float* m  = pca_mean + (size_t)c * Dd;
    const float* cp = comps + ((size_t)(c * Kk + t)) * Dd;
    float s = 0.f;
    #pragma unroll 8
    for (int d = 0; d < Dd; ++d) s = fmaf(m[d], cp[d], s);
    float rv = 1.0f / sqrtf(var[c * Kk + t]);
    w_rv[c * Kk + t] = rv;
    bcs[t] = fmaf(s, rv, mu[c * Kk + t]);
  }
  for (int i = t; i < Kk * Kk; i += 256) M[i] = cov_inv[(size_t)c * Kk * Kk + i];
  __syncthreads();
  for (int j = 0; j < Kk; ++j) {
    if (t == 0) M[j * Kk + j] = sqrtf(M[j * Kk + j]);
    __syncthreads();
    float dj = M[j * Kk + j];
    for (int i = j + 1 + t; i < Kk; i += 256) M[i * Kk + j] /= dj;
    __syncthreads();
    const int rem = Kk - 1 - j;            // rows/cols j+1 .. Kk-1
    for (int idx = t; idx < rem * rem; idx += 256) {
      const int i = j + 1 + idx / rem;
      const int l = j + 1 + idx % rem;
      if (l <= i) M[i * Kk + l] -= M[i * Kk + j] * M[l * Kk + j];
    }
    __syncthreads();
  }
  for (int i = t; i < Kk * Kk; i += 256) Lmat[(size_t)c * Kk * Kk + i] = M[i];
  float s = 0.f;
  if (t < Kk) {
    for (int k = t; k < Kk; ++k) s = fmaf(M[k * Kk + t], bcs[k], s);
  }
  if (t < NCOL) g[c * NCOL + t] = s;
}

// ---------------------------------------------------------------------------
// Prep 3: B in 32x32x16-FRAGMENT-ORDER, split-bf16, 1280 blocks.
// B frag layout (32x32x16): lane l holds col = cg*32 + (l&31),
// k = base + (l>>5)*8 + e. Frag id = kc*4 + ks*2 + cg (hi), +32 (lo);
// frag = 1024 B contiguous; class = 64 frags = 64 KB.
// Element (c, j, d):  kc=d>>5, ks=(d>>4)&1, khalf=(d>>3)&1, e=d&7,
// lane=(j&31)+32*khalf, cg=j>>5.
// Pad class c==19: B=0, g=1e18 (mfma skips it anyway).
// ---------------------------------------------------------------------------
__global__ void prepB_kernel(const float* __restrict__ comps,
                             const float* __restrict__ w_rv,
                             const float* __restrict__ Lmat,
                             float* __restrict__ g,
                             unsigned short* __restrict__ Bs) {
  const int r = blockIdx.x;          // 0..1279
  const int c = r >> 6, j = r & 63;
  const int d = threadIdx.x;         // 0..255
  const int kc = d >> 5, ks = (d >> 4) & 1, kh = (d >> 3) & 1, e = d & 7;
  const int cg = j >> 5, jl = j & 31;
  const unsigned frag = (unsigned)(kc * 4 + ks * 2 + cg);
  const unsigned lane = (unsigned)(jl + 32 * kh);
  const unsigned hi_idx = (unsigned)c * 32768u + frag * 512u + lane * 8u + (unsigned)e;
  const unsigned lo_idx = hi_idx + 32u * 512u;   // lo frag = hi frag + 32
  if (c >= Cc || j >= Kk) {
    Bs[hi_idx] = 0; Bs[lo_idx] = 0;
    if (c >= Cc && d == 0) g[r] = 1e18f;
    return;
  }
  float s = 0.f;
  for (int k = j; k < Kk; ++k)
    s = fmaf(Lmat[(size_t)c * Kk * Kk + k * Kk + j] * w_rv[c * Kk + k],
             comps[((size_t)c * Kk + k) * Dd + d], s);
  unsigned short hi = f2bf(s);
  Bs[hi_idx] = hi;
  Bs[lo_idx] = f2bf(s - bf2f(hi));
}

// ---------------------------------------------------------------------------
// Main: split-bf16 MFMA GEMM on the 32x32x16 shape.
//
// Round-19 change: 16x16x32 -> 32x32x16. uBench: 2382 vs 2075 TF (+15%
// per-FLOP) and 32768 FLOP/instr (2x) -> MFMA issue slots halve in the
// 48%-busy pipe. Wave = 64 px x 64 cols as mf=2 x nf=2 frags of 32x32;
// per 32-k chunk: 16 MFMA phase A / 8 phase B (was 32/16).
// Fragment layouts: A/B lane l -> row/col=l&31, k=(l>>5)*8+j (extrapolated
// from verified 16x16 pattern); C/D col=lane&31,
// row=(reg&3)+8*(reg>>2)+4*(lane>>5) (m74/m101-verified).
// sA NEW layout [k8 0..63][px 0..127] in 16B granules: wave A-frag read =
// 32 consecutive slots -> conflict-free, no swizzle. B re-baked by prepB
// into frag order (1 frag = 1024B coalesced L2-hit load).
// Kept from banked R17: in-chunk A reads, 1-deep B prefetch (R18: 2-deep
// neutral), setprio around MFMA, sched_barrier(0) per chunk (anti-hoist),
// waves_per_eu(2,2) (R12/R13/R15: bigger state or more waves spill).
// ---------------------------------------------------------------------------
__global__ __launch_bounds__(THR)
__attribute__((amdgpu_waves_per_eu(2, 2)))
void mfma_kernel(const float* __restrict__ feats,
                 const unsigned short* __restrict__ Bs,
                 const float* __restrict__ g,
                 float* __restrict__ out) {
  __shared__ unsigned short sA[MT * 512];   // 131072 B: [k8 0..63][px]x16B
  __shared__ unsigned sMin[MT];

  const int tid  = threadIdx.x;
  const int lane = tid & 63;
  const int wid  = tid >> 6;
  const int mh   = wid >> 2;                // 0..1 : rows [mh*64, +64)
  const int slot = wid & 3;                 // class-slot
  const int l31  = lane & 31;
  const int kof  = lane >> 5;               // k-half selector (0/1)
  const size_t pxbase = (size_t)blockIdx.x * MT;

  if (tid < MT) sMin[tid] = 0x7F7FFFFFu;    // FLT_MAX bits

  // ---- Stage A: fp32 feats -> bf16 hi (k8 0..31) | lo (k8 32..63),
  // layout: 16B granule at byte (k8*128 + px)*16.
  {
    const int px  = tid >> 2;
    const int sub = tid & 3;                // k8 groups sub*8 .. +7
    const float4* src = (const float4*)(feats + (pxbase + px) * Dd + sub * 64);
    char* base = (char*)sA;
    #pragma unroll
    for (int i = 0; i < 8; ++i) {
      float4 f0 = src[2 * i];
      float4 f1 = src[2 * i + 1];
      unsigned short h0 = f2bf(f0.x), h1 = f2bf(f0.y), h2 = f2bf(f0.z), h3 = f2bf(f0.w);
      unsigned short h4 = f2bf(f1.x), h5 = f2bf(f1.y), h6 = f2bf(f1.z), h7 = f2bf(f1.w);
      unsigned short l0 = f2bf(f0.x - bf2f(h0)), l1 = f2bf(f0.y - bf2f(h1));
      unsigned short l2 = f2bf(f0.z - bf2f(h2)), l3 = f2bf(f0.w - bf2f(h3));
      unsigned short l4 = f2bf(f1.x - bf2f(h4)), l5 = f2bf(f1.y - bf2f(h5));
      unsigned short l6 = f2bf(f1.z - bf2f(h6)), l7 = f2bf(f1.w - bf2f(h7));
      uint4 hv, lv;
      hv.x = (unsigned)h0 | ((unsigned)h1 << 16); hv.y = (unsigned)h2 | ((unsigned)h3 << 16);
      hv.z = (unsigned)h4 | ((unsigned)h5 << 16); hv.w = (unsigned)h6 | ((unsigned)h7 << 16);
      lv.x = (unsigned)l0 | ((unsigned)l1 << 16); lv.y = (unsigned)l2 | ((unsigned)l3 << 16);
      lv.z = (unsigned)l4 | ((unsigned)l5 << 16); lv.w = (unsigned)l6 | ((unsigned)l7 << 16);
      const int k8 = sub * 8 + i;
      *(uint4*)(base + (k8 * 128 + px) * 16)        = hv;
      *(uint4*)(base + ((k8 + 32) * 128 + px) * 16) = lv;
    }
  }
  __syncthreads();

  // A-frag read bases: byte addr = k8*2048 + row*16
  const unsigned rowb16_0 = (unsigned)((mh * 64 + l31) * 16);
  const unsigned rowb16_1 = rowb16_0 + 32 * 16;
  const char* sAc = (const char*)sA;
  const unsigned koff2048 = (unsigned)(kof * 2048);

  float dmin[2][16];
  #pragma unroll
  for (int mf = 0; mf < 2; ++mf)
    #pragma unroll
    for (int r = 0; r < 16; ++r) dmin[mf][r] = FLT_MAX;

  const unsigned laneB = (unsigned)(lane * 8);   // shorts offset within frag

  #pragma unroll 1
  for (int ci = 0; ci < CPAD / 4; ++ci) {
    const int cl = ci * 4 + slot;
    if (cl >= Cc) continue;                 // wave-uniform dummy-class skip
    const unsigned short* Bb = Bs + (size_t)cl * 32768;

    const float gv0 = g[cl * NCOL + l31];
    const float gv1 = g[cl * NCOL + 32 + l31];

    f32x16 acc[2][2];
    #pragma unroll
    for (int mf = 0; mf < 2; ++mf)
      #pragma unroll
      for (int nf = 0; nf < 2; ++nf) acc[mf][nf] = (f32x16)0.f;

    // ---- prologue: chunk 0's 4 B_hi frags (ks0cg0, ks0cg1, ks1cg0, ks1cg1)
    bf16x8 b0 = *(const bf16x8*)(Bb + 0 * 512 + laneB);
    bf16x8 b1 = *(const bf16x8*)(Bb + 1 * 512 + laneB);
    bf16x8 b2 = *(const bf16x8*)(Bb + 2 * 512 + laneB);
    bf16x8 b3 = *(const bf16x8*)(Bb + 3 * 512 + laneB);

    // ---- phase A: chunks 0..7 (B_hi), A_hi + A_lo read in-chunk.
    // Chunk fg frag base = fg*4 (linear across hi 0..7 then lo 8..15),
    // so tb==7 prefetches frags 32..35 = B_lo chunk 0. 16 MFMA/chunk.
    #pragma unroll
    for (int tb = 0; tb < 8; ++tb) {
      bf16x8 n0 = *(const bf16x8*)(Bb + ((tb + 1) * 4 + 0) * 512 + laneB);
      bf16x8 n1 = *(const bf16x8*)(Bb + ((tb + 1) * 4 + 1) * 512 + laneB);
      bf16x8 n2 = *(const bf16x8*)(Bb + ((tb + 1) * 4 + 2) * 512 + laneB);
      bf16x8 n3 = *(const bf16x8*)(Bb + ((tb + 1) * 4 + 3) * 512 + laneB);
      // A frags: k8 = tb*4 + ks*2 + kof (hi), +32 (lo)
      const unsigned kb = (unsigned)(tb * 4) * 2048u + koff2048;
      bf16x8 aH00 = *(const bf16x8*)(sAc + kb + rowb16_0);
      bf16x8 aH10 = *(const bf16x8*)(sAc + kb + rowb16_1);
      bf16x8 aH01 = *(const bf16x8*)(sAc + kb + 2 * 2048 + rowb16_0);
      bf16x8 aH11 = *(const bf16x8*)(sAc + kb + 2 * 2048 + rowb16_1);
      bf16x8 aL00 = *(const bf16x8*)(sAc + kb + 32 * 2048 + rowb16_0);
      bf16x8 aL10 = *(const bf16x8*)(sAc + kb + 32 * 2048 + rowb16_1);
      bf16x8 aL01 = *(const bf16x8*)(sAc + kb + 34 * 2048 + rowb16_0);
      bf16x8 aL11 = *(const bf16x8*)(sAc + kb + 34 * 2048 + rowb16_1);
      __builtin_amdgcn_s_setprio(1);
      acc[0][0] = __builtin_amdgcn_mfma_f32_32x32x16_bf16(aH00, b0, acc[0][0], 0, 0, 0);
      acc[0][1] = __builtin_amdgcn_mfma_f32_32x32x16_bf16(aH00, b1, acc[0][1], 0, 0, 0);
      acc[1][0] = __builtin_amdgcn_mfma_f32_32x32x16_bf16(aH10, b0, acc[1][0], 0, 0, 0);
      acc[1][1] = __builtin_amdgcn_mfma_f32_32x32x16_bf16(aH10, b1, acc[1][1], 0, 0, 0);
      acc[0][0] = __builtin_amdgcn_mfma_f32_32x32x16_bf16(aH01, b2, acc[0][0], 0, 0, 0);
      acc[0][1] = __builtin_amdgcn_mfma_f32_32x32x16_bf16(aH01, b3, acc[0][1], 0, 0, 0);
      acc[1][0] = __builtin_amdgcn_mfma_f32_32x32x16_bf16(aH11, b2, acc[1][0], 0, 0, 0);
      acc[1][1] = __builtin_amdgcn_mfma_f32_32x32x16_bf16(aH11, b3, acc[1][1], 0, 0, 0);
      acc[0][0] = __builtin_amdgcn_mfma_f32_32x32x16_bf16(aL00, b0, acc[0][0], 0, 0, 0);
      acc[0][1] = __builtin_amdgcn_mfma_f32_32x32x16_bf16(aL00, b1, acc[0][1], 0, 0, 0);
      acc[1][0] = __builtin_amdgcn_mfma_f32_32x32x16_bf16(aL10, b0, acc[1][0], 0, 0, 0);
      acc[1][1] = __builtin_amdgcn_mfma_f32_32x32x16_bf16(aL10, b1, acc[1][1], 0, 0, 0);
      acc[0][0] = __builtin_amdgcn_mfma_f32_32x32x16_bf16(aL01, b2, acc[0][0], 0, 0, 0);
      acc[0][1] = __builtin_amdgcn_mfma_f32_32x32x16_bf16(aL01, b3, acc[0][1], 0, 0, 0);
      acc[1][0] = __builtin_amdgcn_mfma_f32_32x32x16_bf16(aL11, b2, acc[1][0], 0, 0, 0);
      acc[1][1] = __builtin_amdgcn_mfma_f32_32x32x16_bf16(aL11, b3, acc[1][1], 0, 0, 0);
      __builtin_amdgcn_s_setprio(0);
      b0 = n0; b1 = n1; b2 = n2; b3 = n3;
      __builtin_amdgcn_sched_barrier(0);   // keep loads at 1-chunk depth
    }

    // ---- phase B: chunks 8..15 (B_lo), A_hi only. 8 MFMA/chunk.
    #pragma unroll
    for (int tb = 0; tb < 8; ++tb) {
      bf16x8 n0, n1, n2, n3;
      if (tb < 7) {
        n0 = *(const bf16x8*)(Bb + ((9 + tb) * 4 + 0) * 512 + laneB);
        n1 = *(const bf16x8*)(Bb + ((9 + tb) * 4 + 1) * 512 + laneB);
        n2 = *(const bf16x8*)(Bb + ((9 + tb) * 4 + 2) * 512 + laneB);
        n3 = *(const bf16x8*)(Bb + ((9 + tb) * 4 + 3) * 512 + laneB);
      }
      const unsigned kb = (unsigned)(tb * 4) * 2048u + koff2048;
      bf16x8 aH00 = *(const bf16x8*)(sAc + kb + rowb16_0);
      bf16x8 aH10 = *(const bf16x8*)(sAc + kb + rowb16_1);
      bf16x8 aH01 = *(const bf16x8*)(sAc + kb + 2 * 2048 + rowb16_0);
      bf16x8 aH11 = *(const bf16x8*)(sAc + kb + 2 * 2048 + rowb16_1);
      __builtin_amdgcn_s_setprio(1);
      acc[0][0] = __builtin_amdgcn_mfma_f32_32x32x16_bf16(aH00, b0, acc[0][0], 0, 0, 0);
      acc[0][1] = __builtin_amdgcn_mfma_f32_32x32x16_bf16(aH00, b1, acc[0][1], 0, 0, 0);
      acc[1][0] = __builtin_amdgcn_mfma_f32_32x32x16_bf16(aH10, b0, acc[1][0], 0, 0, 0);
      acc[1][1] = __builtin_amdgcn_mfma_f32_32x32x16_bf16(aH10, b1, acc[1][1], 0, 0, 0);
      acc[0][0] = __builtin_amdgcn_mfma_f32_32x32x16_bf16(aH01, b2, acc[0][0], 0, 0, 0);
      acc[0][1] = __builtin_amdgcn_mfma_f32_32x32x16_bf16(aH01, b3, acc[0][1], 0, 0, 0);
      acc[1][0] = __builtin_amdgcn_mfma_f32_32x32x16_bf16(aH11, b2, acc[1][0], 0, 0, 0);
      acc[1][1] = __builtin_amdgcn_mfma_f32_32x32x16_bf16(aH11, b3, acc[1][1], 0, 0, 0);
      __builtin_amdgcn_s_setprio(0);
      if (tb < 7) { b0 = n0; b1 = n1; b2 = n2; b3 = n3; }
      __builtin_amdgcn_sched_barrier(0);
    }

    // ---- epilogue: dist per row; butterfly over 32 cols; running min.
    // C/D: col = cg*32 + (lane&31), row = (r&3)+8*(r>>2)+4*kof (local).
    #pragma unroll
    for (int mf = 0; mf < 2; ++mf) {
      float ps[16];
      #pragma unroll
      for (int r = 0; r < 16; ++r) {
        float t0 = acc[mf][0][r] - gv0;
        float t1 = acc[mf][1][r] - gv1;
        ps[r] = fmaf(t1, t1, t0 * t0);
      }
      #pragma unroll
      for (int off = 1; off < 32; off <<= 1) {
        #pragma unroll
        for (int r = 0; r < 16; ++r) ps[r] += __shfl_xor(ps[r], off);
      }
      #pragma unroll
      for (int r = 0; r < 16; ++r) dmin[mf][r] = fminf(dmin[mf][r], ps[r]);
    }
  }

  // ---- combine the 4 class-slot waves (lanes 0 and 32 hold row-sums)
  if (l31 == 0) {
    #pragma unroll
    for (int mf = 0; mf < 2; ++mf)
      #pragma unroll
      for (int r = 0; r < 16; ++r) {
        int row = mh * 64 + mf * 32 + (r & 3) + 8 * (r >> 2) + 4 * kof;
        atomicMin(&sMin[row], __float_as_uint(dmin[mf][r]));
      }
  }
  __syncthreads();
  if (tid < MT) out[pxbase + tid] = __uint_as_float(sMin[tid]);
}

extern "C" void kernel_launch(void* const* d_in, const int* in_sizes, int n_in,
                              void* d_out, int out_size, void* d_ws, size_t ws_size,
                              hipStream_t stream) {
  const float* feats    = (const float*)d_in[0];
  const float* pca_mean = (const float*)d_in[1];
  const float* comps    = (const float*)d_in[2];
  const float* var      = (const float*)d_in[3];
  const float* mu       = (const float*)d_in[4];
  const float* cov_inv  = (const float*)d_in[5];
  float* out = (float*)d_out;

  // workspace (floats): rv[950] Lmat[47500] g[1280] Bs(bf16)[655360]
  float* w_rv = (float*)d_ws;
  float* Lmat = w_rv + Cc * Kk;
  float* gv   = Lmat + Cc * Kk * Kk;
  unsigned short* Bs = (unsigned short*)(gv + ROWS);

  const int n = in_sizes[0] / Dd;  // 131072 pixels

  prepchol_kernel<<<Cc, 256, 0, stream>>>(pca_mean, comps, var, mu, cov_inv,
                                          w_rv, Lmat, gv);
  prepB_kernel<<<ROWS, 256, 0, stream>>>(comps, w_rv, Lmat, gv, Bs);
  mfma_kernel<<<n / MT, THR, 0, stream>>>(feats, Bs, gv, out);
}

// Round 20
// 276.534 us; speedup vs baseline: 1.1537x; 1.1537x over previous
//
#include <hip/hip_runtime.h>
#include <float.h>
#include <math.h>

// Problem constants (fixed by the reference)
constexpr int Cc = 19;    // classes
constexpr int Kk = 50;    // pca dim
constexpr int Dd = 256;   // feature dim

constexpr int NCOL = 64;          // padded cols per class (50 -> 64)
constexpr int CPAD = 20;          // classes incl 1 dummy pad class (Bs sizing)
constexpr int ROWS = CPAD * NCOL; // 1280 rows of the stacked B matrix
constexpr int MT   = 128;         // pixels per block (proven best geometry)
constexpr int THR  = 512;         // 8 waves

typedef float  f32x4  __attribute__((ext_vector_type(4)));
typedef short  bf16x8 __attribute__((ext_vector_type(8)));

__device__ __forceinline__ unsigned short f2bf(float x) {
  unsigned u = __float_as_uint(x);
  unsigned r = 0x7FFFu + ((u >> 16) & 1u);   // round-to-nearest-even
  return (unsigned short)((u + r) >> 16);
}
__device__ __forceinline__ float bf2f(unsigned short h) {
  return __uint_as_float(((unsigned)h) << 16);
}

// ---------------------------------------------------------------------------
// Prep 1+2 fused: rv = 1/sqrt(var); bc = mean_proj*rv + mu (LDS); Cholesky
// cov_inv = L L^T in LDS (element-parallel trailing update, R16); store
// Lmat and g = L^T bc (0-padded).
// ---------------------------------------------------------------------------
__global__ __launch_bounds__(256) void prepchol_kernel(
    const float* __restrict__ pca_mean,
    const float* __restrict__ comps,
    const float* __restrict__ var,
    const float* __restrict__ mu,
    const float* __restrict__ cov_inv,
    float* __restrict__ w_rv,
    float* __restrict__ Lmat,
    float* __restrict__ g) {
  __shared__ float M[Kk * Kk];
  __shared__ float bcs[Kk];
  const int c = blockIdx.x, t = threadIdx.x;

  if (t < Kk) {
    const float* m  = pca_mean + (size_t)c * Dd;
    const float* cp = comps + ((size_t)(c * Kk + t)) * Dd;
    float s = 0.f;
    #pragma unroll 8
    for (int d = 0; d < Dd; ++d) s = fmaf(m[d], cp[d], s);
    float rv = 1.0f / sqrtf(var[c * Kk + t]);
    w_rv[c * Kk + t] = rv;
    bcs[t] = fmaf(s, rv, mu[c * Kk + t]);
  }
  for (int i = t; i < Kk * Kk; i += 256) M[i] = cov_inv[(size_t)c * Kk * Kk + i];
  __syncthreads();
  for (int j = 0; j < Kk; ++j) {
    if (t == 0) M[j * Kk + j] = sqrtf(M[j * Kk + j]);
    __syncthreads();
    float dj = M[j * Kk + j];
    for (int i = j + 1 + t; i < Kk; i += 256) M[i * Kk + j] /= dj;
    __syncthreads();
    const int rem = Kk - 1 - j;            // rows/cols j+1 .. Kk-1
    for (int idx = t; idx < rem * rem; idx += 256) {
      const int i = j + 1 + idx / rem;
      const int l = j + 1 + idx % rem;
      if (l <= i) M[i * Kk + l] -= M[i * Kk + j] * M[l * Kk + j];
    }
    __syncthreads();
  }
  for (int i = t; i < Kk * Kk; i += 256) Lmat[(size_t)c * Kk * Kk + i] = M[i];
  float s = 0.f;
  if (t < Kk) {
    for (int k = t; k < Kk; ++k) s = fmaf(M[k * Kk + t], bcs[k], s);
  }
  if (t < NCOL) g[c * NCOL + t] = s;
}

// ---------------------------------------------------------------------------
// Prep 3: B in FRAGMENT-ORDER global layout (16x16 frags, R17 layout),
// split-bf16, 1280 blocks. hi chunks 0..7, lo chunks 8..15; chunk =
// [col 0..63][kq 0..3][8 bf16] = 4096 B.
// Pad class c==19: B=0, g=1e18 (mfma skips it anyway).
// ---------------------------------------------------------------------------
__global__ void prepB_kernel(const float* __restrict__ comps,
                             const float* __restrict__ w_rv,
                             const float* __restrict__ Lmat,
                             float* __restrict__ g,
                             unsigned short* __restrict__ Bs) {
  const int r = blockIdx.x;          // 0..1279
  const int c = r >> 6, j = r & 63;
  const int d = threadIdx.x;         // 0..255
  const unsigned hi_idx =
      (unsigned)(c * 16 + (d >> 5)) * 2048u + (unsigned)j * 32u + (unsigned)(d & 31);
  const unsigned lo_idx = hi_idx + 8u * 2048u;   // chunks 8..15
  if (c >= Cc || j >= Kk) {
    Bs[hi_idx] = 0; Bs[lo_idx] = 0;
    if (c >= Cc && d == 0) g[r] = 1e18f;
    return;
  }
  float s = 0.f;
  for (int k = j; k < Kk; ++k)
    s = fmaf(Lmat[(size_t)c * Kk * Kk + k * Kk + j] * w_rv[c * Kk + k],
             comps[((size_t)c * Kk + k) * Dd + d], s);
  unsigned short hi = f2bf(s);
  Bs[hi_idx] = hi;
  Bs[lo_idx] = f2bf(s - bf2f(hi));
}

// ---------------------------------------------------------------------------
// Main: split-bf16 MFMA GEMM (16x16x32 — R19 closed the 32x32 door: fewer,
// longer instrs = less latency cover, 265 vs 215us), B register-streamed
// from L2, A frags read in-chunk (R17), 1-deep B prefetch (R18: 2-deep
// neutral).
//
// Round-20 change: phase B processes B_lo chunks in PAIRS. R17's phase B
// ran 16 MFMA (~77cy) per load batch — half of phase A's cover — and was
// the weak phase dragging MfmaUtil to 48%. Pairing gives 32 MFMA (~155cy)
// per batch (8 B loads + 8 A reads), matching phase A. Pipeline B-state
// in phase B: cur pair 32 + next pair 32 = 64 VGPR — the SAME peak phase A
// already carries (R15's global merge needed 128 and spilled; this doesn't).
// ---------------------------------------------------------------------------
__global__ __launch_bounds__(THR)
__attribute__((amdgpu_waves_per_eu(2, 2)))
void mfma_kernel(const float* __restrict__ feats,
                 const unsigned short* __restrict__ Bs,
                 const float* __restrict__ g,
                 float* __restrict__ out) {
  __shared__ unsigned short sA[MT * 512];   // 131072 B, xor-swizzled
  __shared__ unsigned sMin[MT];

  const int tid  = threadIdx.x;
  const int lane = tid & 63;
  const int wid  = tid >> 6;
  const int mh   = wid >> 2;                // 0..1 : rows [mh*64, +64)
  const int slot = wid & 3;                 // class-slot
  const int l15  = lane & 15;
  const int lk   = (lane >> 4) * 8;         // k-quarter offset (elems)
  const size_t pxbase = (size_t)blockIdx.x * MT;

  if (tid < MT) sMin[tid] = 0x7F7FFFFFu;    // FLT_MAX bits

  // ---- Stage A: fp32 feats -> bf16 hi (elems 0..255) | lo (256..511)
  {
    const int px = tid >> 2;
    const int db = (tid & 3) * 64;
    const float4* src = (const float4*)(feats + (pxbase + px) * Dd + db);
    char* base = (char*)sA;
    #pragma unroll 4
    for (int i = 0; i < 16; ++i) {
      float4 f = src[i];
      int k = db + i * 4;
      unsigned short h0 = f2bf(f.x), h1 = f2bf(f.y), h2 = f2bf(f.z), h3 = f2bf(f.w);
      unsigned short l0 = f2bf(f.x - bf2f(h0)), l1 = f2bf(f.y - bf2f(h1));
      unsigned short l2 = f2bf(f.z - bf2f(h2)), l3 = f2bf(f.w - bf2f(h3));
      uint2 hv, lv;
      hv.x = (unsigned)h0 | ((unsigned)h1 << 16); hv.y = (unsigned)h2 | ((unsigned)h3 << 16);
      lv.x = (unsigned)l0 | ((unsigned)l1 << 16); lv.y = (unsigned)l2 | ((unsigned)l3 << 16);
      unsigned hadr = (unsigned)(px * 1024 + k * 2)         ^ ((px & 7) << 4);
      unsigned ladr = (unsigned)(px * 1024 + (256 + k) * 2) ^ ((px & 7) << 4);
      *(uint2*)(base + hadr) = hv;
      *(uint2*)(base + ladr) = lv;
    }
  }
  __syncthreads();

  // A-frag address components (XOR swizzle applied after row-base + k sum)
  unsigned rowb[4], swr[4];
  #pragma unroll
  for (int mf = 0; mf < 4; ++mf) {
    int row = mh * 64 + mf * 16 + l15;
    rowb[mf] = (unsigned)(row * 1024);
    swr[mf]  = (unsigned)((row & 7) << 4);
  }
  const char* sAc = (const char*)sA;
  const unsigned lk2 = (unsigned)(lk * 2);  // byte offset of kh(0)

  float dmin[4][4];
  #pragma unroll
  for (int mf = 0; mf < 4; ++mf)
    #pragma unroll
    for (int r = 0; r < 4; ++r) dmin[mf][r] = FLT_MAX;

  const unsigned be = (unsigned)(l15 * 32 + lk);   // shorts, within 16-col grp

  #pragma unroll 1
  for (int ci = 0; ci < CPAD / 4; ++ci) {
    const int cl = ci * 4 + slot;
    if (cl >= Cc) continue;                 // wave-uniform dummy-class skip
    const unsigned short* Bb = Bs + (size_t)cl * (16 * 2048);

    float gv[4];
    #pragma unroll
    for (int nf = 0; nf < 4; ++nf) gv[nf] = g[cl * NCOL + nf * 16 + l15];

    f32x4 acc[4][4];
    #pragma unroll
    for (int mf = 0; mf < 4; ++mf)
      #pragma unroll
      for (int nf = 0; nf < 4; ++nf) acc[mf][nf] = (f32x4)0.f;

    // ---- prologue: B chunk 0 into current regs (A is read in-chunk)
    bf16x8 b0 = *(const bf16x8*)(Bb + 0 * 512 + be);
    bf16x8 b1 = *(const bf16x8*)(Bb + 1 * 512 + be);
    bf16x8 b2 = *(const bf16x8*)(Bb + 2 * 512 + be);
    bf16x8 b3 = *(const bf16x8*)(Bb + 3 * 512 + be);

    // ---- phase A: B_hi chunks 0..7, A_hi + A_lo read in-chunk
    #pragma unroll
    for (int tb = 0; tb < 8; ++tb) {
      // next-chunk B prefetch (tb==7 feeds phase B chunk 8 = B_lo 0)
      bf16x8 n0 = *(const bf16x8*)(Bb + (tb + 1) * 2048 + 0 * 512 + be);
      bf16x8 n1 = *(const bf16x8*)(Bb + (tb + 1) * 2048 + 1 * 512 + be);
      bf16x8 n2 = *(const bf16x8*)(Bb + (tb + 1) * 2048 + 2 * 512 + be);
      bf16x8 n3 = *(const bf16x8*)(Bb + (tb + 1) * 2048 + 3 * 512 + be);
      const unsigned kh = (unsigned)(tb * 64) + lk2;
      bf16x8 cH[4], cL[4];
      #pragma unroll
      for (int mf = 0; mf < 4; ++mf)
        cH[mf] = *(const bf16x8*)(sAc + ((rowb[mf] + kh) ^ swr[mf]));
      #pragma unroll
      for (int mf = 0; mf < 4; ++mf)
        cL[mf] = *(const bf16x8*)(sAc + ((rowb[mf] + kh + 512) ^ swr[mf]));
      __builtin_amdgcn_s_setprio(1);
      #pragma unroll
      for (int mf = 0; mf < 4; ++mf) {
        acc[mf][0] = __builtin_amdgcn_mfma_f32_16x16x32_bf16(cH[mf], b0, acc[mf][0], 0, 0, 0);
        acc[mf][1] = __builtin_amdgcn_mfma_f32_16x16x32_bf16(cH[mf], b1, acc[mf][1], 0, 0, 0);
        acc[mf][2] = __builtin_amdgcn_mfma_f32_16x16x32_bf16(cH[mf], b2, acc[mf][2], 0, 0, 0);
        acc[mf][3] = __builtin_amdgcn_mfma_f32_16x16x32_bf16(cH[mf], b3, acc[mf][3], 0, 0, 0);
      }
      #pragma unroll
      for (int mf = 0; mf < 4; ++mf) {
        acc[mf][0] = __builtin_amdgcn_mfma_f32_16x16x32_bf16(cL[mf], b0, acc[mf][0], 0, 0, 0);
        acc[mf][1] = __builtin_amdgcn_mfma_f32_16x16x32_bf16(cL[mf], b1, acc[mf][1], 0, 0, 0);
        acc[mf][2] = __builtin_amdgcn_mfma_f32_16x16x32_bf16(cL[mf], b2, acc[mf][2], 0, 0, 0);
        acc[mf][3] = __builtin_amdgcn_mfma_f32_16x16x32_bf16(cL[mf], b3, acc[mf][3], 0, 0, 0);
      }
      __builtin_amdgcn_s_setprio(0);
      b0 = n0; b1 = n1; b2 = n2; b3 = n3;
      __builtin_amdgcn_sched_barrier(0);   // keep loads at 1-chunk depth
    }

    // ---- phase B: B_lo chunks 8..15 in PAIRS, A_hi only, read in-chunk.
    // Entering: b0..b3 = chunk 8 (phase A tb=7 prefetch). Load chunk 9 now.
    bf16x8 e0 = *(const bf16x8*)(Bb + 9 * 2048 + 0 * 512 + be);
    bf16x8 e1 = *(const bf16x8*)(Bb + 9 * 2048 + 1 * 512 + be);
    bf16x8 e2 = *(const bf16x8*)(Bb + 9 * 2048 + 2 * 512 + be);
    bf16x8 e3 = *(const bf16x8*)(Bb + 9 * 2048 + 3 * 512 + be);
    #pragma unroll
    for (int tb = 0; tb < 4; ++tb) {
      bf16x8 q0, q1, q2, q3, r0, r1, r2, r3;
      if (tb < 3) {
        q0 = *(const bf16x8*)(Bb + (10 + 2 * tb) * 2048 + 0 * 512 + be);
        q1 = *(const bf16x8*)(Bb + (10 + 2 * tb) * 2048 + 1 * 512 + be);
        q2 = *(const bf16x8*)(Bb + (10 + 2 * tb) * 2048 + 2 * 512 + be);
        q3 = *(const bf16x8*)(Bb + (10 + 2 * tb) * 2048 + 3 * 512 + be);
        r0 = *(const bf16x8*)(Bb + (11 + 2 * tb) * 2048 + 0 * 512 + be);
        r1 = *(const bf16x8*)(Bb + (11 + 2 * tb) * 2048 + 1 * 512 + be);
        r2 = *(const bf16x8*)(Bb + (11 + 2 * tb) * 2048 + 2 * 512 + be);
        r3 = *(const bf16x8*)(Bb + (11 + 2 * tb) * 2048 + 3 * 512 + be);
      }
      const unsigned kh0 = (unsigned)((2 * tb) * 64) + lk2;
      const unsigned kh1 = (unsigned)((2 * tb + 1) * 64) + lk2;
      bf16x8 cH0[4], cH1[4];
      #pragma unroll
      for (int mf = 0; mf < 4; ++mf)
        cH0[mf] = *(const bf16x8*)(sAc + ((rowb[mf] + kh0) ^ swr[mf]));
      #pragma unroll
      for (int mf = 0; mf < 4; ++mf)
        cH1[mf] = *(const bf16x8*)(sAc + ((rowb[mf] + kh1) ^ swr[mf]));
      __builtin_amdgcn_s_setprio(1);
      #pragma unroll
      for (int mf = 0; mf < 4; ++mf) {
        acc[mf][0] = __builtin_amdgcn_mfma_f32_16x16x32_bf16(cH0[mf], b0, acc[mf][0], 0, 0, 0);
        acc[mf][1] = __builtin_amdgcn_mfma_f32_16x16x32_bf16(cH0[mf], b1, acc[mf][1], 0, 0, 0);
        acc[mf][2] = __builtin_amdgcn_mfma_f32_16x16x32_bf16(cH0[mf], b2, acc[mf][2], 0, 0, 0);
        acc[mf][3] = __builtin_amdgcn_mfma_f32_16x16x32_bf16(cH0[mf], b3, acc[mf][3], 0, 0, 0);
      }
      #pragma unroll
      for (int mf = 0; mf < 4; ++mf) {
        acc[mf][0] = __builtin_amdgcn_mfma_f32_16x16x32_bf16(cH1[mf], e0, acc[mf][0], 0, 0, 0);
        acc[mf][1] = __builtin_amdgcn_mfma_f32_16x16x32_bf16(cH1[mf], e1, acc[mf][1], 0, 0, 0);
        acc[mf][2] = __builtin_amdgcn_mfma_f32_16x16x32_bf16(cH1[mf], e2, acc[mf][2], 0, 0, 0);
        acc[mf][3] = __builtin_amdgcn_mfma_f32_16x16x32_bf16(cH1[mf], e3, acc[mf][3], 0, 0, 0);
      }
      __builtin_amdgcn_s_setprio(0);
      if (tb < 3) {
        b0 = q0; b1 = q1; b2 = q2; b3 = q3;
        e0 = r0; e1 = r1; e2 = r2; e3 = r3;
      }
      __builtin_amdgcn_sched_barrier(0);
    }

    // ---- epilogue: complete dist for this class, per row; running min
    #pragma unroll
    for (int mf = 0; mf < 4; ++mf) {
      float ps0 = 0.f, ps1 = 0.f, ps2 = 0.f, ps3 = 0.f;
      #pragma unroll
      for (int nf = 0; nf < 4; ++nf) {
        float gg = gv[nf];
        float t0 = acc[mf][nf][0] - gg; ps0 = fmaf(t0, t0, ps0);
        float t1 = acc[mf][nf][1] - gg; ps1 = fmaf(t1, t1, ps1);
        float t2 = acc[mf][nf][2] - gg; ps2 = fmaf(t2, t2, ps2);
        float t3 = acc[mf][nf][3] - gg; ps3 = fmaf(t3, t3, ps3);
      }
      #pragma unroll
      for (int off = 1; off < 16; off <<= 1) {
        ps0 += __shfl_xor(ps0, off);
        ps1 += __shfl_xor(ps1, off);
        ps2 += __shfl_xor(ps2, off);
        ps3 += __shfl_xor(ps3, off);
      }
      dmin[mf][0] = fminf(dmin[mf][0], ps0);
      dmin[mf][1] = fminf(dmin[mf][1], ps1);
      dmin[mf][2] = fminf(dmin[mf][2], ps2);
      dmin[mf][3] = fminf(dmin[mf][3], ps3);
    }
  }

  // ---- combine the 4 class-slot waves per row-half
  if (l15 == 0) {
    #pragma unroll
    for (int mf = 0; mf < 4; ++mf)
      #pragma unroll
      for (int r = 0; r < 4; ++r) {
        int row = mh * 64 + mf * 16 + (lane >> 4) * 4 + r;
        atomicMin(&sMin[row], __float_as_uint(dmin[mf][r]));
      }
  }
  __syncthreads();
  if (tid < MT) out[pxbase + tid] = __uint_as_float(sMin[tid]);
}

extern "C" void kernel_launch(void* const* d_in, const int* in_sizes, int n_in,
                              void* d_out, int out_size, void* d_ws, size_t ws_size,
                              hipStream_t stream) {
  const float* feats    = (const float*)d_in[0];
  const float* pca_mean = (const float*)d_in[1];
  const float* comps    = (const float*)d_in[2];
  const float* var      = (const float*)d_in[3];
  const float* mu       = (const float*)d_in[4];
  const float* cov_inv  = (const float*)d_in[5];
  float* out = (float*)d_out;

  // workspace (floats): rv[950] Lmat[47500] g[1280] Bs(bf16)[655360]
  float* w_rv = (float*)d_ws;
  float* Lmat = w_rv + Cc * Kk;
  float* gv   = Lmat + Cc * Kk * Kk;
  unsigned short* Bs = (unsigned short*)(gv + ROWS);

  const int n = in_sizes[0] / Dd;  // 131072 pixels

  prepchol_kernel<<<Cc, 256, 0, stream>>>(pca_mean, comps, var, mu, cov_inv,
                                          w_rv, Lmat, gv);
  prepB_kernel<<<ROWS, 256, 0, stream>>>(comps, w_rv, Lmat, gv, Bs);
  mfma_kernel<<<n / MT, THR, 0, stream>>>(feats, Bs, gv, out);
}

// Round 21
// 268.513 us; speedup vs baseline: 1.1881x; 1.0299x over previous
//
#include <hip/hip_runtime.h>
#include <float.h>
#include <math.h>

// Problem constants (fixed by the reference)
constexpr int Cc = 19;    // classes
constexpr int Kk = 50;    // pca dim
constexpr int Dd = 256;   // feature dim

constexpr int NCOL = 64;          // padded cols per class (50 -> 64)
constexpr int CPAD = 20;          // classes incl 1 dummy pad class (Bs sizing)
constexpr int ROWS = CPAD * NCOL; // 1280 rows of the stacked B matrix
constexpr int MT   = 128;         // pixels per block (proven best geometry)
constexpr int THR  = 512;         // 8 waves

typedef float  f32x4  __attribute__((ext_vector_type(4)));
typedef short  bf16x8 __attribute__((ext_vector_type(8)));

__device__ __forceinline__ unsigned short f2bf(float x) {
  unsigned u = __float_as_uint(x);
  unsigned r = 0x7FFFu + ((u >> 16) & 1u);   // round-to-nearest-even
  return (unsigned short)((u + r) >> 16);
}
__device__ __forceinline__ float bf2f(unsigned short h) {
  return __uint_as_float(((unsigned)h) << 16);
}

// ---------------------------------------------------------------------------
// Prep 1+2 fused: rv = 1/sqrt(var); bc = mean_proj*rv + mu (LDS); Cholesky
// cov_inv = L L^T in LDS (element-parallel trailing update, R16); store
// Lmat and g = L^T bc (0-padded).
// ---------------------------------------------------------------------------
__global__ __launch_bounds__(256) void prepchol_kernel(
    const float* __restrict__ pca_mean,
    const float* __restrict__ comps,
    const float* __restrict__ var,
    const float* __restrict__ mu,
    const float* __restrict__ cov_inv,
    float* __restrict__ w_rv,
    float* __restrict__ Lmat,
    float* __restrict__ g) {
  __shared__ float M[Kk * Kk];
  __shared__ float bcs[Kk];
  const int c = blockIdx.x, t = threadIdx.x;

  if (t < Kk) {
    const float* m  = pca_mean + (size_t)c * Dd;
    const float* cp = comps + ((size_t)(c * Kk + t)) * Dd;
    float s = 0.f;
    #pragma unroll 8
    for (int d = 0; d < Dd; ++d) s = fmaf(m[d], cp[d], s);
    float rv = 1.0f / sqrtf(var[c * Kk + t]);
    w_rv[c * Kk + t] = rv;
    bcs[t] = fmaf(s, rv, mu[c * Kk + t]);
  }
  for (int i = t; i < Kk * Kk; i += 256) M[i] = cov_inv[(size_t)c * Kk * Kk + i];
  __syncthreads();
  for (int j = 0; j < Kk; ++j) {
    if (t == 0) M[j * Kk + j] = sqrtf(M[j * Kk + j]);
    __syncthreads();
    float dj = M[j * Kk + j];
    for (int i = j + 1 + t; i < Kk; i += 256) M[i * Kk + j] /= dj;
    __syncthreads();
    const int rem = Kk - 1 - j;            // rows/cols j+1 .. Kk-1
    for (int idx = t; idx < rem * rem; idx += 256) {
      const int i = j + 1 + idx / rem;
      const int l = j + 1 + idx % rem;
      if (l <= i) M[i * Kk + l] -= M[i * Kk + j] * M[l * Kk + j];
    }
    __syncthreads();
  }
  for (int i = t; i < Kk * Kk; i += 256) Lmat[(size_t)c * Kk * Kk + i] = M[i];
  float s = 0.f;
  if (t < Kk) {
    for (int k = t; k < Kk; ++k) s = fmaf(M[k * Kk + t], bcs[k], s);
  }
  if (t < NCOL) g[c * NCOL + t] = s;
}

// ---------------------------------------------------------------------------
// Prep 3: B in FRAGMENT-ORDER global layout, split-bf16, 1280 blocks (one
// per padded row — whole chip participates; Round-10 lesson).
// B[c][j][d] = sum_{k>=j} L[k][j]*rv[k]*comps[c][k][d]; hi chunks 0..7,
// residual lo chunks 8..15; chunk = [col 0..63][kq 0..3][8 bf16] = 4096 B.
// Pad class c==19: B=0, g=1e18 (mfma skips it anyway).
// ---------------------------------------------------------------------------
__global__ void prepB_kernel(const float* __restrict__ comps,
                             const float* __restrict__ w_rv,
                             const float* __restrict__ Lmat,
                             float* __restrict__ g,
                             unsigned short* __restrict__ Bs) {
  const int r = blockIdx.x;          // 0..1279
  const int c = r >> 6, j = r & 63;
  const int d = threadIdx.x;         // 0..255
  const unsigned hi_idx =
      (unsigned)(c * 16 + (d >> 5)) * 2048u + (unsigned)j * 32u + (unsigned)(d & 31);
  const unsigned lo_idx = hi_idx + 8u * 2048u;   // chunks 8..15
  if (c >= Cc || j >= Kk) {
    Bs[hi_idx] = 0; Bs[lo_idx] = 0;
    if (c >= Cc && d == 0) g[r] = 1e18f;
    return;
  }
  float s = 0.f;
  for (int k = j; k < Kk; ++k)
    s = fmaf(Lmat[(size_t)c * Kk * Kk + k * Kk + j] * w_rv[c * Kk + k],
             comps[((size_t)c * Kk + k) * Dd + d], s);
  unsigned short hi = f2bf(s);
  Bs[hi_idx] = hi;
  Bs[lo_idx] = f2bf(s - bf2f(hi));
}

// ---------------------------------------------------------------------------
// Main: split-bf16 MFMA GEMM, B register-streamed from L2 — the R17
// operating point, session best (268.6us total; mfma 215us steady, 48.4%
// MfmaUtil, VGPR 120, zero spill).
//
// Closed doors (all measured): B-in-LDS (R6); 4 waves/EU (R12/R13 spill);
// phase merge (R15 spill); A-prefetch (R10 vs R17: dropping it +9%);
// 2-deep B prefetch (R18 neutral); 32x32 shape (R19 -23%); phase-B
// pairing (R20 -4%). Structure: in-chunk A reads, 1-deep B prefetch,
// setprio around MFMA, sched_barrier(0) per chunk (anti-hoist fence).
// Ceiling: MFMA-busy 104us = 2075-TF floor; residual 111us = load latency
// at 2 waves/SIMD, pinned jointly by LDS (131.6KB -> 1 block/CU) and
// unified-register demand (~184/wave -> 2 waves/SIMD).
// ---------------------------------------------------------------------------
__global__ __launch_bounds__(THR)
__attribute__((amdgpu_waves_per_eu(3, 3)))
void mfma_kernel(const float* __restrict__ feats,
                 const unsigned short* __restrict__ Bs,
                 const float* __restrict__ g,
                 float* __restrict__ out) {
  __shared__ unsigned short sA[MT * 512];   // 131072 B, xor-swizzled
  __shared__ unsigned sMin[MT];

  const int tid  = threadIdx.x;
  const int lane = tid & 63;
  const int wid  = tid >> 6;
  const int mh   = wid >> 2;                // 0..1 : rows [mh*64, +64)
  const int slot = wid & 3;                 // class-slot
  const int l15  = lane & 15;
  const int lk   = (lane >> 4) * 8;         // k-quarter offset (elems)
  const size_t pxbase = (size_t)blockIdx.x * MT;

  if (tid < MT) sMin[tid] = 0x7F7FFFFFu;    // FLT_MAX bits

  // ---- Stage A: fp32 feats -> bf16 hi (elems 0..255) | lo (256..511)
  {
    const int px = tid >> 2;
    const int db = (tid & 3) * 64;
    const float4* src = (const float4*)(feats + (pxbase + px) * Dd + db);
    char* base = (char*)sA;
    #pragma unroll 4
    for (int i = 0; i < 16; ++i) {
      float4 f = src[i];
      int k = db + i * 4;
      unsigned short h0 = f2bf(f.x), h1 = f2bf(f.y), h2 = f2bf(f.z), h3 = f2bf(f.w);
      unsigned short l0 = f2bf(f.x - bf2f(h0)), l1 = f2bf(f.y - bf2f(h1));
      unsigned short l2 = f2bf(f.z - bf2f(h2)), l3 = f2bf(f.w - bf2f(h3));
      uint2 hv, lv;
      hv.x = (unsigned)h0 | ((unsigned)h1 << 16); hv.y = (unsigned)h2 | ((unsigned)h3 << 16);
      lv.x = (unsigned)l0 | ((unsigned)l1 << 16); lv.y = (unsigned)l2 | ((unsigned)l3 << 16);
      unsigned hadr = (unsigned)(px * 1024 + k * 2)         ^ ((px & 7) << 4);
      unsigned ladr = (unsigned)(px * 1024 + (256 + k) * 2) ^ ((px & 7) << 4);
      *(uint2*)(base + hadr) = hv;
      *(uint2*)(base + ladr) = lv;
    }
  }
  __syncthreads();

  // A-frag address components (XOR swizzle applied after row-base + k sum)
  unsigned rowb[4], swr[4];
  #pragma unroll
  for (int mf = 0; mf < 4; ++mf) {
    int row = mh * 64 + mf * 16 + l15;
    rowb[mf] = (unsigned)(row * 1024);
    swr[mf]  = (unsigned)((row & 7) << 4);
  }
  const char* sAc = (const char*)sA;
  const unsigned lk2 = (unsigned)(lk * 2);  // byte offset of kh(0)

  float dmin[4][4];
  #pragma unroll
  for (int mf = 0; mf < 4; ++mf)
    #pragma unroll
    for (int r = 0; r < 4; ++r) dmin[mf][r] = FLT_MAX;

  const unsigned be = (unsigned)(l15 * 32 + lk);   // shorts, within 16-col grp

  #pragma unroll 1
  for (int ci = 0; ci < CPAD / 4; ++ci) {
    const int cl = ci * 4 + slot;
    if (cl >= Cc) continue;                 // wave-uniform dummy-class skip
    const unsigned short* Bb = Bs + (size_t)cl * (16 * 2048);

    float gv[4];
    #pragma unroll
    for (int nf = 0; nf < 4; ++nf) gv[nf] = g[cl * NCOL + nf * 16 + l15];

    f32x4 acc[4][4];
    #pragma unroll
    for (int mf = 0; mf < 4; ++mf)
      #pragma unroll
      for (int nf = 0; nf < 4; ++nf) acc[mf][nf] = (f32x4)0.f;

    // ---- prologue: B chunk 0 into current regs (A is read in-chunk)
    bf16x8 b0 = *(const bf16x8*)(Bb + 0 * 512 + be);
    bf16x8 b1 = *(const bf16x8*)(Bb + 1 * 512 + be);
    bf16x8 b2 = *(const bf16x8*)(Bb + 2 * 512 + be);
    bf16x8 b3 = *(const bf16x8*)(Bb + 3 * 512 + be);

    // ---- phase A: B_hi chunks 0..7, A_hi + A_lo read in-chunk
    #pragma unroll
    for (int tb = 0; tb < 8; ++tb) {
      // next-chunk B prefetch (tb==7 feeds phase B chunk 8 = B_lo 0)
      bf16x8 n0 = *(const bf16x8*)(Bb + (tb + 1) * 2048 + 0 * 512 + be);
      bf16x8 n1 = *(const bf16x8*)(Bb + (tb + 1) * 2048 + 1 * 512 + be);
      bf16x8 n2 = *(const bf16x8*)(Bb + (tb + 1) * 2048 + 2 * 512 + be);
      bf16x8 n3 = *(const bf16x8*)(Bb + (tb + 1) * 2048 + 3 * 512 + be);
      const unsigned kh = (unsigned)(tb * 64) + lk2;
      bf16x8 cH[4], cL[4];
      #pragma unroll
      for (int mf = 0; mf < 4; ++mf)
        cH[mf] = *(const bf16x8*)(sAc + ((rowb[mf] + kh) ^ swr[mf]));
      #pragma unroll
      for (int mf = 0; mf < 4; ++mf)
        cL[mf] = *(const bf16x8*)(sAc + ((rowb[mf] + kh + 512) ^ swr[mf]));
      __builtin_amdgcn_s_setprio(1);
      #pragma unroll
      for (int mf = 0; mf < 4; ++mf) {
        acc[mf][0] = __builtin_amdgcn_mfma_f32_16x16x32_bf16(cH[mf], b0, acc[mf][0], 0, 0, 0);
        acc[mf][1] = __builtin_amdgcn_mfma_f32_16x16x32_bf16(cH[mf], b1, acc[mf][1], 0, 0, 0);
        acc[mf][2] = __builtin_amdgcn_mfma_f32_16x16x32_bf16(cH[mf], b2, acc[mf][2], 0, 0, 0);
        acc[mf][3] = __builtin_amdgcn_mfma_f32_16x16x32_bf16(cH[mf], b3, acc[mf][3], 0, 0, 0);
      }
      #pragma unroll
      for (int mf = 0; mf < 4; ++mf) {
        acc[mf][0] = __builtin_amdgcn_mfma_f32_16x16x32_bf16(cL[mf], b0, acc[mf][0], 0, 0, 0);
        acc[mf][1] = __builtin_amdgcn_mfma_f32_16x16x32_bf16(cL[mf], b1, acc[mf][1], 0, 0, 0);
        acc[mf][2] = __builtin_amdgcn_mfma_f32_16x16x32_bf16(cL[mf], b2, acc[mf][2], 0, 0, 0);
        acc[mf][3] = __builtin_amdgcn_mfma_f32_16x16x32_bf16(cL[mf], b3, acc[mf][3], 0, 0, 0);
      }
      __builtin_amdgcn_s_setprio(0);
      b0 = n0; b1 = n1; b2 = n2; b3 = n3;
      __builtin_amdgcn_sched_barrier(0);   // keep loads at 1-chunk depth
    }

    // ---- phase B: B_lo chunks 8..15, A_hi only, read in-chunk
    #pragma unroll
    for (int tb = 0; tb < 8; ++tb) {
      bf16x8 n0, n1, n2, n3;
      if (tb < 7) {
        n0 = *(const bf16x8*)(Bb + (9 + tb) * 2048 + 0 * 512 + be);
        n1 = *(const bf16x8*)(Bb + (9 + tb) * 2048 + 1 * 512 + be);
        n2 = *(const bf16x8*)(Bb + (9 + tb) * 2048 + 2 * 512 + be);
        n3 = *(const bf16x8*)(Bb + (9 + tb) * 2048 + 3 * 512 + be);
      }
      const unsigned kh = (unsigned)(tb * 64) + lk2;
      bf16x8 cH[4];
      #pragma unroll
      for (int mf = 0; mf < 4; ++mf)
        cH[mf] = *(const bf16x8*)(sAc + ((rowb[mf] + kh) ^ swr[mf]));
      __builtin_amdgcn_s_setprio(1);
      #pragma unroll
      for (int mf = 0; mf < 4; ++mf) {
        acc[mf][0] = __builtin_amdgcn_mfma_f32_16x16x32_bf16(cH[mf], b0, acc[mf][0], 0, 0, 0);
        acc[mf][1] = __builtin_amdgcn_mfma_f32_16x16x32_bf16(cH[mf], b1, acc[mf][1], 0, 0, 0);
        acc[mf][2] = __builtin_amdgcn_mfma_f32_16x16x32_bf16(cH[mf], b2, acc[mf][2], 0, 0, 0);
        acc[mf][3] = __builtin_amdgcn_mfma_f32_16x16x32_bf16(cH[mf], b3, acc[mf][3], 0, 0, 0);
      }
      __builtin_amdgcn_s_setprio(0);
      if (tb < 7) { b0 = n0; b1 = n1; b2 = n2; b3 = n3; }
      __builtin_amdgcn_sched_barrier(0);
    }

    // ---- epilogue: complete dist for this class, per row; running min
    #pragma unroll
    for (int mf = 0; mf < 4; ++mf) {
      float ps0 = 0.f, ps1 = 0.f, ps2 = 0.f, ps3 = 0.f;
      #pragma unroll
      for (int nf = 0; nf < 4; ++nf) {
        float gg = gv[nf];
        float t0 = acc[mf][nf][0] - gg; ps0 = fmaf(t0, t0, ps0);
        float t1 = acc[mf][nf][1] - gg; ps1 = fmaf(t1, t1, ps1);
        float t2 = acc[mf][nf][2] - gg; ps2 = fmaf(t2, t2, ps2);
        float t3 = acc[mf][nf][3] - gg; ps3 = fmaf(t3, t3, ps3);
      }
      #pragma unroll
      for (int off = 1; off < 16; off <<= 1) {
        ps0 += __shfl_xor(ps0, off);
        ps1 += __shfl_xor(ps1, off);
        ps2 += __shfl_xor(ps2, off);
        ps3 += __shfl_xor(ps3, off);
      }
      dmin[mf][0] = fminf(dmin[mf][0], ps0);
      dmin[mf][1] = fminf(dmin[mf][1], ps1);
      dmin[mf][2] = fminf(dmin[mf][2], ps2);
      dmin[mf][3] = fminf(dmin[mf][3], ps3);
    }
  }

  // ---- combine the 4 class-slot waves per row-half
  if (l15 == 0) {
    #pragma unroll
    for (int mf = 0; mf < 4; ++mf)
      #pragma unroll
      for (int r = 0; r < 4; ++r) {
        int row = mh * 64 + mf * 16 + (lane >> 4) * 4 + r;
        atomicMin(&sMin[row], __float_as_uint(dmin[mf][r]));
      }
  }
  __syncthreads();
  if (tid < MT) out[pxbase + tid] = __uint_as_float(sMin[tid]);
}

extern "C" void kernel_launch(void* const* d_in, const int* in_sizes, int n_in,
                              void* d_out, int out_size, void* d_ws, size_t ws_size,
                              hipStream_t stream) {
  const float* feats    = (const float*)d_in[0];
  const float* pca_mean = (const float*)d_in[1];
  const float* comps    = (const float*)d_in[2];
  const float* var      = (const float*)d_in[3];
  const float* mu       = (const float*)d_in[4];
  const float* cov_inv  = (const float*)d_in[5];
  float* out = (float*)d_out;

  // workspace (floats): rv[950] Lmat[47500] g[1280] Bs(bf16)[655360]
  float* w_rv = (float*)d_ws;
  float* Lmat = w_rv + Cc * Kk;
  float* gv   = Lmat + Cc * Kk * Kk;
  unsigned short* Bs = (unsigned short*)(gv + ROWS);

  const int n = in_sizes[0] / Dd;  // 131072 pixels

  prepchol_kernel<<<Cc, 256, 0, stream>>>(pca_mean, comps, var, mu, cov_inv,
                                          w_rv, Lmat, gv);
  prepB_kernel<<<ROWS, 256, 0, stream>>>(comps, w_rv, Lmat, gv, Bs);
  mfma_kernel<<<n / MT, THR, 0, stream>>>(feats, Bs, gv, out);
}